// Round 26
// baseline (257.718 us; speedup 1.0000x reference)
//
#include <hip/hip_runtime.h>
#include <hip/hip_bf16.h>
#include <math.h>

#define NB 2
#define NN 512
#define CS 256
#define CP 128
#define FD 64
#define NBINS 22
#define EPB 64

typedef __attribute__((ext_vector_type(8))) short bf16x8;
typedef __attribute__((ext_vector_type(4))) short bf16x4;
typedef __attribute__((ext_vector_type(4))) float f32x4;

__device__ __forceinline__ unsigned short f2bf_rne(float x) {
    unsigned int u = __float_as_uint(x);
    unsigned int r = (u + 0x7fffu + ((u >> 16) & 1u)) >> 16;
    return (unsigned short)r;
}
__device__ __forceinline__ float bf2f(unsigned short b) {
    return __uint_as_float(((unsigned int)b) << 16);
}
__device__ __forceinline__ unsigned short f2bf(float x) {
    __hip_bfloat16 h = __float2bfloat16(x);
    unsigned short u;
    __builtin_memcpy(&u, &h, 2);
    return u;
}

// Guarded-floor bin: exact fp32 boundary semantics of the reference scan.
__device__ __forceinline__ int bin_of(float d, float step) {
    const float fk = __fdiv_rn(__fsub_rn(d, 0.001f), step);
    int k0 = (int)fk;
    k0 = k0 < 1 ? 1 : (k0 > 20 ? 20 : k0);
    int row = -1;
    #pragma unroll
    for (int dk = -1; dk <= 1; ++dk) {
        const int k = k0 + dk;
        const float lo = __fadd_rn(0.001f, __fmul_rn((float)k, step));
        const float hi = (k == NBINS - 1)
                       ? 1e8f
                       : __fadd_rn(0.001f, __fmul_rn((float)(k + 1), step));
        row = (d > lo && d < hi) ? k : row;
    }
    return row;
}

// ---------------------------------------------------------------------------
// Prep kernel (r23-proven), three segments:
//   [0,1024): per-node q/r; [1024,1088): W pack; [1088,3136): per-edge bins.
// ---------------------------------------------------------------------------
__global__ __launch_bounds__(256) void ef_prep_kernel(
    const float* __restrict__ x,
    const float* __restrict__ diffuse,
    const float* __restrict__ Wsp,
    const float* __restrict__ bsp,
    const float* __restrict__ W1,
    const float* __restrict__ b1,
    const float* __restrict__ W2,
    const float* __restrict__ W3,
    const float* __restrict__ trans_t,
    const float* __restrict__ trans_sc,
    float* __restrict__ qr,
    unsigned short* __restrict__ Wp,
    unsigned short* __restrict__ binsP)
{
    __shared__ float xs[CS];
    __shared__ float ps[FD];
    const int t = threadIdx.x;
    if (blockIdx.x < 1024) {
        const int n = blockIdx.x;
        xs[t] = x[(size_t)n * CS + t];
        __syncthreads();
        if (t < FD) {
            float acc = bsp[t];
            #pragma unroll 8
            for (int k = 0; k < CS; ++k)
                acc = fmaf(xs[k], Wsp[k * FD + t], acc);
            ps[t] = acc;
        }
        __syncthreads();
        const float dm = diffuse[n];
        const int c = t & (CP - 1);
        if (t < CP) {
            float acc = b1[c] + dm * W1[172 * CP + c];
            #pragma unroll 8
            for (int k = 0; k < FD; ++k)
                acc = fmaf(ps[k], W1[k * CP + c], acc);
            qr[(size_t)n * CP + c] = acc;
        } else {
            float acc = dm * W1[173 * CP + c];
            #pragma unroll 8
            for (int k = 0; k < FD; ++k)
                acc = fmaf(ps[k], W1[(FD + k) * CP + c], acc);
            qr[(size_t)(1024 + n) * CP + c] = acc;
        }
    } else if (blockIdx.x < 1088) {
        const int s = (blockIdx.x - 1024) * 256 + t;   // 0..16383
        const int j    = s & 7;
        const int lane = (s >> 3) & 63;
        const int mt   = (s >> 9) & 7;
        const int ki   = s >> 12;
        const int k = 32 * ki + 8 * (lane >> 4) + j;
        const int n = 16 * mt + (lane & 15);
        Wp[s]         = f2bf_rne(W2[k * CP + n]);
        Wp[16384 + s] = f2bf_rne(W3[k * CP + n]);
    } else {
        const int e  = (blockIdx.x - 1088) * 256 + t;  // 0..524287
        const int bb = e >> 18;
        const int ii = (e >> 9) & (NN - 1);
        const int jj = e & (NN - 1);
        const int ni = bb * NN + ii;
        const int nj = bb * NN + jj;
        const float step = __fdiv_rn(__fsub_rn(20.0f, 0.001f), 21.0f);
        float dx = __fsub_rn(trans_t[ni * 3 + 0], trans_t[nj * 3 + 0]);
        float dy = __fsub_rn(trans_t[ni * 3 + 1], trans_t[nj * 3 + 1]);
        float dz = __fsub_rn(trans_t[ni * 3 + 2], trans_t[nj * 3 + 2]);
        const float dT = sqrtf(__fadd_rn(__fadd_rn(__fmul_rn(dx, dx), __fmul_rn(dy, dy)), __fmul_rn(dz, dz)));
        dx = __fsub_rn(trans_sc[ni * 3 + 0], trans_sc[nj * 3 + 0]);
        dy = __fsub_rn(trans_sc[ni * 3 + 1], trans_sc[nj * 3 + 1]);
        dz = __fsub_rn(trans_sc[ni * 3 + 2], trans_sc[nj * 3 + 2]);
        const float dS = sqrtf(__fadd_rn(__fadd_rn(__fmul_rn(dx, dx), __fmul_rn(dy, dy)), __fmul_rn(dz, dz)));
        const int kT = bin_of(dT, step);
        const int kS = bin_of(dS, step);
        binsP[e] = (unsigned short)((unsigned int)(kT + 1) | ((unsigned int)(kS + 1) << 8));
    }
}

// ---------------------------------------------------------------------------
// Edge kernel: PERSISTENT (b,i) blocks — grid 1024 = exactly 4 blocks/CU.
// Each block loops over its 8 j-tiles; the per-tile body is byte-identical
// to the r23 champion (181 us edge). NOTHING is held across iterations
// (r4's spill trap was persistent W-frags; here every tile value is
// loop-local). Zero block turnover, zero dispatch tail, perfect balance.
// 7 barriers/tile (champion 6 + loop-end barrier protecting LN scratch).
// ---------------------------------------------------------------------------
__global__ __launch_bounds__(256, 4) void ef_edge_kernel(
    const float* __restrict__ edge_mask,
    const float* __restrict__ W1,
    const float* __restrict__ b2,
    const float* __restrict__ b3,
    const float* __restrict__ ln_g,
    const float* __restrict__ ln_b,
    const float* __restrict__ qr,
    const unsigned short* __restrict__ Wp,
    const unsigned short* __restrict__ binsP,
    float* __restrict__ out)
{
    __shared__ unsigned short hb[8192];    // 16384 B: h1-plane, then h2-plane
    char* hb8 = (char*)hb;
    float* psum_s  = (float*)hb8;            // [64][17]  (4352 B)
    float* pqsum_s = (float*)(hb8 + 4352);   // [64][17]  (4352 B)
    float* mus     = (float*)(hb8 + 8704);   // [64]
    float* invs    = (float*)(hb8 + 8960);   // [64]      (ends 9216 <= 16384)

    const int t   = threadIdx.x;
    const int blk = blockIdx.x;             // 0..1023
    const int i   = blk & (NN - 1);
    const int b   = blk >> 9;
    const int nodeI = b * NN + i;

    const int w  = t >> 6;
    const int l  = t & 63;
    const int lr = l & 15;
    const int lg = l >> 4;
    const int e1 = t >> 2;
    const int c0 = (t & 3) * 32;

    #pragma unroll 1
    for (int jt = 0; jt < 8; ++jt) {
        const int j0 = jt * EPB;
        const int nj = b * NN + j0 + e1;

        // ---- bins: one 2-byte load (precomputed) ----
        const size_t erow0 = ((size_t)(b * NN + i)) * NN + (j0 + e1);
        const unsigned int pk = binsP[erow0];
        const int kT = (int)(pk & 0xffu) - 1;
        const int kS = (int)(pk >> 8) - 1;

        // ---- P1: h1 = relu(q_i + r_j + W1[binT] + W1[binS]) -> H plane ----
        {
            const float fT = (kT < 0) ? 0.0f : 1.0f;
            const float fS = (kS < 0) ? 0.0f : 1.0f;
            const float* qrow = qr + (size_t)nodeI * CP + c0;
            const float* rrow = qr + (size_t)(1024 + nj) * CP + c0;
            const float* wTr  = W1 + (size_t)(kT < 0 ? 0 : 128 + kT) * CP + c0;
            const float* wSr  = W1 + (size_t)(kS < 0 ? 0 : 150 + kS) * CP + c0;
            #pragma unroll
            for (int ch = 0; ch < 4; ++ch) {
                const int cc = ch * 8;
                const float4 qa = *(const float4*)(qrow + cc);
                const float4 qb = *(const float4*)(qrow + cc + 4);
                const float4 ra = *(const float4*)(rrow + cc);
                const float4 rb = *(const float4*)(rrow + cc + 4);
                const float4 ta = *(const float4*)(wTr + cc);
                const float4 tb = *(const float4*)(wTr + cc + 4);
                const float4 sa = *(const float4*)(wSr + cc);
                const float4 sb = *(const float4*)(wSr + cc + 4);
                float h[8];
                h[0] = fmaxf(qa.x + ra.x + fT * ta.x + fS * sa.x, 0.0f);
                h[1] = fmaxf(qa.y + ra.y + fT * ta.y + fS * sa.y, 0.0f);
                h[2] = fmaxf(qa.z + ra.z + fT * ta.z + fS * sa.z, 0.0f);
                h[3] = fmaxf(qa.w + ra.w + fT * ta.w + fS * sa.w, 0.0f);
                h[4] = fmaxf(qb.x + rb.x + fT * tb.x + fS * sb.x, 0.0f);
                h[5] = fmaxf(qb.y + rb.y + fT * tb.y + fS * sb.y, 0.0f);
                h[6] = fmaxf(qb.z + rb.z + fT * tb.z + fS * sb.z, 0.0f);
                h[7] = fmaxf(qb.w + rb.w + fT * tb.w + fS * sb.w, 0.0f);
                bf16x8 H;
                #pragma unroll
                for (int u = 0; u < 8; ++u)
                    H[u] = (short)f2bf(h[u]);
                const unsigned int ad = (unsigned int)e1 * 256 +
                    (((unsigned int)(2 * (c0 + cc))) ^ (((unsigned int)e1 & 7) << 4));
                *(bf16x8*)(hb8 + ad) = H;
            }
        }
        __syncthreads();   // barrier 1: h1 ready

        // ---- P2: layer-2 MFMA: C = W2_bf16 . h1_bf16 ----
        f32x4 acc[2][4];
        #pragma unroll
        for (int mt = 0; mt < 2; ++mt) {
            const float4 bv = *(const float4*)&b2[16 * (2 * w + mt) + 4 * lg];
            #pragma unroll
            for (int nt = 0; nt < 4; ++nt) {
                acc[mt][nt][0] = bv.x; acc[mt][nt][1] = bv.y;
                acc[mt][nt][2] = bv.z; acc[mt][nt][3] = bv.w;
            }
        }
        #pragma unroll
        for (int ki = 0; ki < 4; ++ki) {
            bf16x8 ah[2];
            #pragma unroll
            for (int mt = 0; mt < 2; ++mt) {
                const size_t off = (((size_t)ki * 8 + (2 * w + mt)) * 64 + l) * 8;
                ah[mt] = *(const bf16x8*)(Wp + off);
            }
            bf16x8 bh[4];
            #pragma unroll
            for (int nt = 0; nt < 4; ++nt) {
                const int e = 16 * nt + lr;
                const unsigned int ad = (unsigned int)e * 256 +
                    (((unsigned int)(64 * ki + 16 * lg)) ^ (((unsigned int)e & 7) << 4));
                bh[nt] = *(const bf16x8*)(hb8 + ad);
            }
            __builtin_amdgcn_s_setprio(1);
            #pragma unroll
            for (int mt = 0; mt < 2; ++mt)
                #pragma unroll
                for (int nt = 0; nt < 4; ++nt)
                    acc[mt][nt] = __builtin_amdgcn_mfma_f32_16x16x32_bf16(ah[mt], bh[nt], acc[mt][nt], 0, 0, 0);
            __builtin_amdgcn_s_setprio(0);
        }
        __syncthreads();   // barrier 2: all h1 reads done; hb reusable for h2

        // ---- P3: h2 = relu(acc) -> H plane, transposed [e][n] ----
        #pragma unroll
        for (int mt = 0; mt < 2; ++mt) {
            const int mtg = 2 * w + mt;
            #pragma unroll
            for (int nt = 0; nt < 4; ++nt) {
                const int e = 16 * nt + lr;
                bf16x4 H;
                H[0] = (short)f2bf(fmaxf(acc[mt][nt][0], 0.0f));
                H[1] = (short)f2bf(fmaxf(acc[mt][nt][1], 0.0f));
                H[2] = (short)f2bf(fmaxf(acc[mt][nt][2], 0.0f));
                H[3] = (short)f2bf(fmaxf(acc[mt][nt][3], 0.0f));
                const unsigned int ad = (unsigned int)e * 256 +
                    (((unsigned int)(32 * mtg + 8 * lg)) ^ (((unsigned int)e & 7) << 4));
                *(bf16x4*)(hb8 + ad) = H;
            }
        }
        __syncthreads();   // barrier 3: h2 ready

        // ---- P4: layer-3 MFMA into the SAME acc (re-init with b3) ----
        #pragma unroll
        for (int mt = 0; mt < 2; ++mt) {
            const float4 bv = *(const float4*)&b3[16 * (2 * w + mt) + 4 * lg];
            #pragma unroll
            for (int nt = 0; nt < 4; ++nt) {
                acc[mt][nt][0] = bv.x; acc[mt][nt][1] = bv.y;
                acc[mt][nt][2] = bv.z; acc[mt][nt][3] = bv.w;
            }
        }
        #pragma unroll
        for (int ki = 0; ki < 4; ++ki) {
            bf16x8 ah[2];
            #pragma unroll
            for (int mt = 0; mt < 2; ++mt) {
                const size_t off = (((size_t)ki * 8 + (2 * w + mt)) * 64 + l) * 8;
                ah[mt] = *(const bf16x8*)(Wp + 16384 + off);
            }
            bf16x8 bh[4];
            #pragma unroll
            for (int nt = 0; nt < 4; ++nt) {
                const int e = 16 * nt + lr;
                const unsigned int ad = (unsigned int)e * 256 +
                    (((unsigned int)(64 * ki + 16 * lg)) ^ (((unsigned int)e & 7) << 4));
                bh[nt] = *(const bf16x8*)(hb8 + ad);
            }
            __builtin_amdgcn_s_setprio(1);
            #pragma unroll
            for (int mt = 0; mt < 2; ++mt)
                #pragma unroll
                for (int nt = 0; nt < 4; ++nt)
                    acc[mt][nt] = __builtin_amdgcn_mfma_f32_16x16x32_bf16(ah[mt], bh[nt], acc[mt][nt], 0, 0, 0);
            __builtin_amdgcn_s_setprio(0);
        }
        __syncthreads();   // barrier 4: all h2 reads done; hb reusable for LN

        // ---- P5: LN partial sums -> [64][17] arrays ----
        #pragma unroll
        for (int nt = 0; nt < 4; ++nt) {
            const int e = 16 * nt + lr;
            float s = 0.0f, s2 = 0.0f;
            #pragma unroll
            for (int mt = 0; mt < 2; ++mt)
                #pragma unroll
                for (int r = 0; r < 4; ++r) {
                    const float v = acc[mt][nt][r];
                    s += v;
                    s2 = fmaf(v, v, s2);
                }
            psum_s[e * 17 + 4 * w + lg]  = s;
            pqsum_s[e * 17 + 4 * w + lg] = s2;
        }
        __syncthreads();   // barrier 5

        // ---- P6: LN reduce (redundant per thread, e = t & 63) ----
        {
            const int e = t & 63;
            float s = 0.0f, s2 = 0.0f;
            #pragma unroll
            for (int k = 0; k < 16; ++k) {
                s  += psum_s[e * 17 + k];
                s2 += pqsum_s[e * 17 + k];
            }
            const float mu  = s * (1.0f / 128.0f);
            const float var = s2 * (1.0f / 128.0f) - mu * mu;
            mus[e]  = mu;
            invs[e] = rsqrtf(var + 1e-5f);
        }
        __syncthreads();   // barrier 6: mus/invs ready

        // ---- P7: normalize fragments in-register, mask, direct frag store ----
        {
            float4 g4[2], bb4[2];
            #pragma unroll
            for (int mt = 0; mt < 2; ++mt) {
                const int n0 = 16 * (2 * w + mt) + 4 * lg;
                g4[mt]  = *(const float4*)&ln_g[n0];
                bb4[mt] = *(const float4*)&ln_b[n0];
            }
            #pragma unroll
            for (int nt = 0; nt < 4; ++nt) {
                const int e = 16 * nt + lr;
                const size_t erow = ((size_t)(b * NN + i)) * NN + (j0 + e);
                const float em  = edge_mask[erow];
                const float mu  = mus[e];
                const float inv = invs[e];
                float* op = out + erow * CP;
                #pragma unroll
                for (int mt = 0; mt < 2; ++mt) {
                    const int n0 = 16 * (2 * w + mt) + 4 * lg;
                    float4 o;
                    o.x = ((acc[mt][nt][0] - mu) * inv * g4[mt].x + bb4[mt].x) * em;
                    o.y = ((acc[mt][nt][1] - mu) * inv * g4[mt].y + bb4[mt].y) * em;
                    o.z = ((acc[mt][nt][2] - mu) * inv * g4[mt].z + bb4[mt].z) * em;
                    o.w = ((acc[mt][nt][3] - mu) * inv * g4[mt].w + bb4[mt].w) * em;
                    *(float4*)(op + n0) = o;
                }
            }
        }
        __syncthreads();   // barrier 7: protect LN scratch before next P1
    }
}

extern "C" void kernel_launch(void* const* d_in, const int* in_sizes, int n_in,
                              void* d_out, int out_size, void* d_ws, size_t ws_size,
                              hipStream_t stream) {
    const float* init_node = (const float*)d_in[0];
    const float* trans_t   = (const float*)d_in[1];
    const float* trans_sc  = (const float*)d_in[2];
    const float* edge_mask = (const float*)d_in[3];
    const float* diffuse   = (const float*)d_in[4];
    const float* Wsp       = (const float*)d_in[5];
    const float* bsp       = (const float*)d_in[6];
    const float* W1        = (const float*)d_in[7];
    const float* b1        = (const float*)d_in[8];
    const float* W2        = (const float*)d_in[9];
    const float* b2        = (const float*)d_in[10];
    const float* W3        = (const float*)d_in[11];
    const float* b3        = (const float*)d_in[12];
    const float* ln_g      = (const float*)d_in[13];
    const float* ln_b      = (const float*)d_in[14];
    float* out = (float*)d_out;
    float* qr  = (float*)d_ws;                                            // 1 MiB
    unsigned short* Wp    = (unsigned short*)((char*)d_ws + (1 << 20));   // 64 KiB
    unsigned short* binsP = (unsigned short*)((char*)d_ws + (1 << 20) + 65536); // 1 MiB

    ef_prep_kernel<<<1024 + 64 + 2048, 256, 0, stream>>>(
        init_node, diffuse, Wsp, bsp, W1, b1, W2, W3, trans_t, trans_sc,
        qr, Wp, binsP);
    ef_edge_kernel<<<NB * NN, 256, 0, stream>>>(
        edge_mask, W1, b2, b3, ln_g, ln_b, qr, Wp, binsP, out);
}

// Round 27
// 185.802 us; speedup vs baseline: 1.3871x; 1.3871x over previous
//
#include <hip/hip_runtime.h>
#include <hip/hip_bf16.h>
#include <math.h>

#define NB 2
#define NN 512
#define CS 256
#define CP 128
#define FD 64
#define NBINS 22
#define EPB 64

typedef __attribute__((ext_vector_type(8))) short bf16x8;
typedef __attribute__((ext_vector_type(4))) short bf16x4;
typedef __attribute__((ext_vector_type(4))) float f32x4;

__device__ __forceinline__ unsigned short f2bf_rne(float x) {
    unsigned int u = __float_as_uint(x);
    unsigned int r = (u + 0x7fffu + ((u >> 16) & 1u)) >> 16;
    return (unsigned short)r;
}
__device__ __forceinline__ float bf2f(unsigned short b) {
    return __uint_as_float(((unsigned int)b) << 16);
}
__device__ __forceinline__ unsigned short f2bf(float x) {
    __hip_bfloat16 h = __float2bfloat16(x);
    unsigned short u;
    __builtin_memcpy(&u, &h, 2);
    return u;
}

// Guarded-floor bin: exact fp32 boundary semantics of the reference scan.
__device__ __forceinline__ int bin_of(float d, float step) {
    const float fk = __fdiv_rn(__fsub_rn(d, 0.001f), step);
    int k0 = (int)fk;
    k0 = k0 < 1 ? 1 : (k0 > 20 ? 20 : k0);
    int row = -1;
    #pragma unroll
    for (int dk = -1; dk <= 1; ++dk) {
        const int k = k0 + dk;
        const float lo = __fadd_rn(0.001f, __fmul_rn((float)k, step));
        const float hi = (k == NBINS - 1)
                       ? 1e8f
                       : __fadd_rn(0.001f, __fmul_rn((float)(k + 1), step));
        row = (d > lo && d < hi) ? k : row;
    }
    return row;
}

// ---------------------------------------------------------------------------
// Prep kernel (r23-proven), three segments:
//   [0,1024): per-node q/r; [1024,1088): W pack; [1088,3136): per-edge bins.
// ---------------------------------------------------------------------------
__global__ __launch_bounds__(256) void ef_prep_kernel(
    const float* __restrict__ x,
    const float* __restrict__ diffuse,
    const float* __restrict__ Wsp,
    const float* __restrict__ bsp,
    const float* __restrict__ W1,
    const float* __restrict__ b1,
    const float* __restrict__ W2,
    const float* __restrict__ W3,
    const float* __restrict__ trans_t,
    const float* __restrict__ trans_sc,
    float* __restrict__ qr,
    unsigned short* __restrict__ Wp,
    unsigned short* __restrict__ binsP)
{
    __shared__ float xs[CS];
    __shared__ float ps[FD];
    const int t = threadIdx.x;
    if (blockIdx.x < 1024) {
        const int n = blockIdx.x;
        xs[t] = x[(size_t)n * CS + t];
        __syncthreads();
        if (t < FD) {
            float acc = bsp[t];
            #pragma unroll 8
            for (int k = 0; k < CS; ++k)
                acc = fmaf(xs[k], Wsp[k * FD + t], acc);
            ps[t] = acc;
        }
        __syncthreads();
        const float dm = diffuse[n];
        const int c = t & (CP - 1);
        if (t < CP) {
            float acc = b1[c] + dm * W1[172 * CP + c];
            #pragma unroll 8
            for (int k = 0; k < FD; ++k)
                acc = fmaf(ps[k], W1[k * CP + c], acc);
            qr[(size_t)n * CP + c] = acc;
        } else {
            float acc = dm * W1[173 * CP + c];
            #pragma unroll 8
            for (int k = 0; k < FD; ++k)
                acc = fmaf(ps[k], W1[(FD + k) * CP + c], acc);
            qr[(size_t)(1024 + n) * CP + c] = acc;
        }
    } else if (blockIdx.x < 1088) {
        const int s = (blockIdx.x - 1024) * 256 + t;   // 0..16383
        const int j    = s & 7;
        const int lane = (s >> 3) & 63;
        const int mt   = (s >> 9) & 7;
        const int ki   = s >> 12;
        const int k = 32 * ki + 8 * (lane >> 4) + j;
        const int n = 16 * mt + (lane & 15);
        Wp[s]         = f2bf_rne(W2[k * CP + n]);
        Wp[16384 + s] = f2bf_rne(W3[k * CP + n]);
    } else {
        const int e  = (blockIdx.x - 1088) * 256 + t;  // 0..524287
        const int bb = e >> 18;
        const int ii = (e >> 9) & (NN - 1);
        const int jj = e & (NN - 1);
        const int ni = bb * NN + ii;
        const int nj = bb * NN + jj;
        const float step = __fdiv_rn(__fsub_rn(20.0f, 0.001f), 21.0f);
        float dx = __fsub_rn(trans_t[ni * 3 + 0], trans_t[nj * 3 + 0]);
        float dy = __fsub_rn(trans_t[ni * 3 + 1], trans_t[nj * 3 + 1]);
        float dz = __fsub_rn(trans_t[ni * 3 + 2], trans_t[nj * 3 + 2]);
        const float dT = sqrtf(__fadd_rn(__fadd_rn(__fmul_rn(dx, dx), __fmul_rn(dy, dy)), __fmul_rn(dz, dz)));
        dx = __fsub_rn(trans_sc[ni * 3 + 0], trans_sc[nj * 3 + 0]);
        dy = __fsub_rn(trans_sc[ni * 3 + 1], trans_sc[nj * 3 + 1]);
        dz = __fsub_rn(trans_sc[ni * 3 + 2], trans_sc[nj * 3 + 2]);
        const float dS = sqrtf(__fadd_rn(__fadd_rn(__fmul_rn(dx, dx), __fmul_rn(dy, dy)), __fmul_rn(dz, dz)));
        const int kT = bin_of(dT, step);
        const int kS = bin_of(dS, step);
        binsP[e] = (unsigned short)((unsigned int)(kT + 1) | ((unsigned int)(kS + 1) << 8));
    }
}

// ---------------------------------------------------------------------------
// Edge kernel: the r25 champion, byte-for-byte (185.96 us total, passed).
// One 64-edge tile per block, 4 waves, single-plane bf16 weights,
// precomputed bins, batched A-loads pinned with sched_barrier(0).
// ---------------------------------------------------------------------------
__global__ __launch_bounds__(256, 4) void ef_edge_kernel(
    const float* __restrict__ edge_mask,
    const float* __restrict__ W1,
    const float* __restrict__ b2,
    const float* __restrict__ b3,
    const float* __restrict__ ln_g,
    const float* __restrict__ ln_b,
    const float* __restrict__ qr,
    const unsigned short* __restrict__ Wp,
    const unsigned short* __restrict__ binsP,
    float* __restrict__ out)
{
    __shared__ unsigned short hb[8192];    // 16384 B: h1-plane, then h2-plane
    char* hb8 = (char*)hb;
    float* psum_s  = (float*)hb8;            // [64][17]  (4352 B)
    float* pqsum_s = (float*)(hb8 + 4352);   // [64][17]  (4352 B)
    float* mus     = (float*)(hb8 + 8704);   // [64]
    float* invs    = (float*)(hb8 + 8960);   // [64]      (ends 9216 <= 16384)

    const int t   = threadIdx.x;
    const int blk = blockIdx.x;
    const int jt  = blk & 7;
    const int i   = (blk >> 3) & (NN - 1);
    const int b   = blk >> 12;
    const int j0  = jt * EPB;
    const int nodeI  = b * NN + i;
    const int nodeJ0 = b * NN + j0;

    const int w  = t >> 6;
    const int l  = t & 63;
    const int lr = l & 15;
    const int lg = l >> 4;
    const int e1 = t >> 2;
    const int c0 = (t & 3) * 32;
    const int nj = nodeJ0 + e1;

    // ---- bins: one 2-byte load (precomputed) ----
    const size_t erow0 = ((size_t)(b * NN + i)) * NN + (j0 + e1);
    const unsigned int pk = binsP[erow0];
    const int kT = (int)(pk & 0xffu) - 1;
    const int kS = (int)(pk >> 8) - 1;

    // ---- P1: h1 = relu(q_i + r_j + W1[binT] + W1[binS]) -> LDS (H plane) ----
    {
        const float fT = (kT < 0) ? 0.0f : 1.0f;
        const float fS = (kS < 0) ? 0.0f : 1.0f;
        const float* qrow = qr + (size_t)nodeI * CP + c0;
        const float* rrow = qr + (size_t)(1024 + nj) * CP + c0;
        const float* wTr  = W1 + (size_t)(kT < 0 ? 0 : 128 + kT) * CP + c0;
        const float* wSr  = W1 + (size_t)(kS < 0 ? 0 : 150 + kS) * CP + c0;
        #pragma unroll
        for (int ch = 0; ch < 4; ++ch) {
            const int cc = ch * 8;
            const float4 qa = *(const float4*)(qrow + cc);
            const float4 qb = *(const float4*)(qrow + cc + 4);
            const float4 ra = *(const float4*)(rrow + cc);
            const float4 rb = *(const float4*)(rrow + cc + 4);
            const float4 ta = *(const float4*)(wTr + cc);
            const float4 tb = *(const float4*)(wTr + cc + 4);
            const float4 sa = *(const float4*)(wSr + cc);
            const float4 sb = *(const float4*)(wSr + cc + 4);
            float h[8];
            h[0] = fmaxf(qa.x + ra.x + fT * ta.x + fS * sa.x, 0.0f);
            h[1] = fmaxf(qa.y + ra.y + fT * ta.y + fS * sa.y, 0.0f);
            h[2] = fmaxf(qa.z + ra.z + fT * ta.z + fS * sa.z, 0.0f);
            h[3] = fmaxf(qa.w + ra.w + fT * ta.w + fS * sa.w, 0.0f);
            h[4] = fmaxf(qb.x + rb.x + fT * tb.x + fS * sb.x, 0.0f);
            h[5] = fmaxf(qb.y + rb.y + fT * tb.y + fS * sb.y, 0.0f);
            h[6] = fmaxf(qb.z + rb.z + fT * tb.z + fS * sb.z, 0.0f);
            h[7] = fmaxf(qb.w + rb.w + fT * tb.w + fS * sb.w, 0.0f);
            bf16x8 H;
            #pragma unroll
            for (int u = 0; u < 8; ++u)
                H[u] = (short)f2bf(h[u]);
            const unsigned int ad = (unsigned int)e1 * 256 +
                (((unsigned int)(2 * (c0 + cc))) ^ (((unsigned int)e1 & 7) << 4));
            *(bf16x8*)(hb8 + ad) = H;
        }
    }

    // ---- batched load of ALL W2 A-frags (issues before the barrier wait) ----
    bf16x8 ahAll[4][2];
    #pragma unroll
    for (int ki = 0; ki < 4; ++ki)
        #pragma unroll
        for (int mt = 0; mt < 2; ++mt)
            ahAll[ki][mt] = *(const bf16x8*)(Wp + (((size_t)ki * 8 + (2 * w + mt)) * 64 + l) * 8);
    __builtin_amdgcn_sched_barrier(0);   // pin: loads may not sink past here
    __syncthreads();   // barrier 1: h1 ready

    // ---- P2: layer-2 MFMA: C = W2_bf16 . h1_bf16 (A-frags in registers) ----
    f32x4 acc[2][4];
    #pragma unroll
    for (int mt = 0; mt < 2; ++mt) {
        const float4 bv = *(const float4*)&b2[16 * (2 * w + mt) + 4 * lg];
        #pragma unroll
        for (int nt = 0; nt < 4; ++nt) {
            acc[mt][nt][0] = bv.x; acc[mt][nt][1] = bv.y;
            acc[mt][nt][2] = bv.z; acc[mt][nt][3] = bv.w;
        }
    }
    #pragma unroll
    for (int ki = 0; ki < 4; ++ki) {
        bf16x8 bh[4];
        #pragma unroll
        for (int nt = 0; nt < 4; ++nt) {
            const int e = 16 * nt + lr;
            const unsigned int ad = (unsigned int)e * 256 +
                (((unsigned int)(64 * ki + 16 * lg)) ^ (((unsigned int)e & 7) << 4));
            bh[nt] = *(const bf16x8*)(hb8 + ad);
        }
        __builtin_amdgcn_s_setprio(1);
        #pragma unroll
        for (int mt = 0; mt < 2; ++mt)
            #pragma unroll
            for (int nt = 0; nt < 4; ++nt)
                acc[mt][nt] = __builtin_amdgcn_mfma_f32_16x16x32_bf16(ahAll[ki][mt], bh[nt], acc[mt][nt], 0, 0, 0);
        __builtin_amdgcn_s_setprio(0);
    }

    // ---- batched load of ALL W3 A-frags (hides under barrier 2 + P3) ----
    #pragma unroll
    for (int ki = 0; ki < 4; ++ki)
        #pragma unroll
        for (int mt = 0; mt < 2; ++mt)
            ahAll[ki][mt] = *(const bf16x8*)(Wp + 16384 + (((size_t)ki * 8 + (2 * w + mt)) * 64 + l) * 8);
    __builtin_amdgcn_sched_barrier(0);   // pin
    __syncthreads();   // barrier 2: all h1 reads done; hb reusable for h2

    // ---- P3: h2 = relu(acc) -> LDS (H plane only), transposed [e][n] ----
    #pragma unroll
    for (int mt = 0; mt < 2; ++mt) {
        const int mtg = 2 * w + mt;
        #pragma unroll
        for (int nt = 0; nt < 4; ++nt) {
            const int e = 16 * nt + lr;
            bf16x4 H;
            H[0] = (short)f2bf(fmaxf(acc[mt][nt][0], 0.0f));
            H[1] = (short)f2bf(fmaxf(acc[mt][nt][1], 0.0f));
            H[2] = (short)f2bf(fmaxf(acc[mt][nt][2], 0.0f));
            H[3] = (short)f2bf(fmaxf(acc[mt][nt][3], 0.0f));
            const unsigned int ad = (unsigned int)e * 256 +
                (((unsigned int)(32 * mtg + 8 * lg)) ^ (((unsigned int)e & 7) << 4));
            *(bf16x4*)(hb8 + ad) = H;
        }
    }
    __syncthreads();   // barrier 3: h2 ready

    // ---- P4: layer-3 MFMA into the SAME acc (re-init with b3) ----
    #pragma unroll
    for (int mt = 0; mt < 2; ++mt) {
        const float4 bv = *(const float4*)&b3[16 * (2 * w + mt) + 4 * lg];
        #pragma unroll
        for (int nt = 0; nt < 4; ++nt) {
            acc[mt][nt][0] = bv.x; acc[mt][nt][1] = bv.y;
            acc[mt][nt][2] = bv.z; acc[mt][nt][3] = bv.w;
        }
    }
    #pragma unroll
    for (int ki = 0; ki < 4; ++ki) {
        bf16x8 bh[4];
        #pragma unroll
        for (int nt = 0; nt < 4; ++nt) {
            const int e = 16 * nt + lr;
            const unsigned int ad = (unsigned int)e * 256 +
                (((unsigned int)(64 * ki + 16 * lg)) ^ (((unsigned int)e & 7) << 4));
            bh[nt] = *(const bf16x8*)(hb8 + ad);
        }
        __builtin_amdgcn_s_setprio(1);
        #pragma unroll
        for (int mt = 0; mt < 2; ++mt)
            #pragma unroll
            for (int nt = 0; nt < 4; ++nt)
                acc[mt][nt] = __builtin_amdgcn_mfma_f32_16x16x32_bf16(ahAll[ki][mt], bh[nt], acc[mt][nt], 0, 0, 0);
        __builtin_amdgcn_s_setprio(0);
    }
    __syncthreads();   // barrier 4: all h2 reads done; hb reusable for LN

    // ---- P5: LN partial sums -> [64][17] arrays ----
    #pragma unroll
    for (int nt = 0; nt < 4; ++nt) {
        const int e = 16 * nt + lr;
        float s = 0.0f, s2 = 0.0f;
        #pragma unroll
        for (int mt = 0; mt < 2; ++mt)
            #pragma unroll
            for (int r = 0; r < 4; ++r) {
                const float v = acc[mt][nt][r];
                s += v;
                s2 = fmaf(v, v, s2);
            }
        psum_s[e * 17 + 4 * w + lg]  = s;
        pqsum_s[e * 17 + 4 * w + lg] = s2;
    }
    __syncthreads();   // barrier 5

    // ---- P6: LN reduce (redundant per thread, e = t & 63) ----
    {
        const int e = t & 63;
        float s = 0.0f, s2 = 0.0f;
        #pragma unroll
        for (int k = 0; k < 16; ++k) {
            s  += psum_s[e * 17 + k];
            s2 += pqsum_s[e * 17 + k];
        }
        const float mu  = s * (1.0f / 128.0f);
        const float var = s2 * (1.0f / 128.0f) - mu * mu;
        mus[e]  = mu;
        invs[e] = rsqrtf(var + 1e-5f);
    }
    __syncthreads();   // barrier 6

    // ---- P7: normalize fragments in-register, mask, direct frag store ----
    {
        float4 g4[2], bb4[2];
        #pragma unroll
        for (int mt = 0; mt < 2; ++mt) {
            const int n0 = 16 * (2 * w + mt) + 4 * lg;
            g4[mt]  = *(const float4*)&ln_g[n0];
            bb4[mt] = *(const float4*)&ln_b[n0];
        }
        #pragma unroll
        for (int nt = 0; nt < 4; ++nt) {
            const int e = 16 * nt + lr;
            const size_t erow = ((size_t)(b * NN + i)) * NN + (j0 + e);
            const float em  = edge_mask[erow];
            const float mu  = mus[e];
            const float inv = invs[e];
            float* op = out + erow * CP;
            #pragma unroll
            for (int mt = 0; mt < 2; ++mt) {
                const int n0 = 16 * (2 * w + mt) + 4 * lg;
                float4 o;
                o.x = ((acc[mt][nt][0] - mu) * inv * g4[mt].x + bb4[mt].x) * em;
                o.y = ((acc[mt][nt][1] - mu) * inv * g4[mt].y + bb4[mt].y) * em;
                o.z = ((acc[mt][nt][2] - mu) * inv * g4[mt].z + bb4[mt].z) * em;
                o.w = ((acc[mt][nt][3] - mu) * inv * g4[mt].w + bb4[mt].w) * em;
                *(float4*)(op + n0) = o;
            }
        }
    }
}

extern "C" void kernel_launch(void* const* d_in, const int* in_sizes, int n_in,
                              void* d_out, int out_size, void* d_ws, size_t ws_size,
                              hipStream_t stream) {
    const float* init_node = (const float*)d_in[0];
    const float* trans_t   = (const float*)d_in[1];
    const float* trans_sc  = (const float*)d_in[2];
    const float* edge_mask = (const float*)d_in[3];
    const float* diffuse   = (const float*)d_in[4];
    const float* Wsp       = (const float*)d_in[5];
    const float* bsp       = (const float*)d_in[6];
    const float* W1        = (const float*)d_in[7];
    const float* b1        = (const float*)d_in[8];
    const float* W2        = (const float*)d_in[9];
    const float* b2        = (const float*)d_in[10];
    const float* W3        = (const float*)d_in[11];
    const float* b3        = (const float*)d_in[12];
    const float* ln_g      = (const float*)d_in[13];
    const float* ln_b      = (const float*)d_in[14];
    float* out = (float*)d_out;
    float* qr  = (float*)d_ws;                                            // 1 MiB
    unsigned short* Wp    = (unsigned short*)((char*)d_ws + (1 << 20));   // 64 KiB
    unsigned short* binsP = (unsigned short*)((char*)d_ws + (1 << 20) + 65536); // 1 MiB

    ef_prep_kernel<<<1024 + 64 + 2048, 256, 0, stream>>>(
        init_node, diffuse, Wsp, bsp, W1, b1, W2, W3, trans_t, trans_sc,
        qr, Wp, binsP);
    ef_edge_kernel<<<NB * NN * (NN / EPB), 256, 0, stream>>>(
        edge_mask, W1, b2, b3, ln_g, ln_b, qr, Wp, binsP, out);
}